// Round 5
// baseline (367.072 us; speedup 1.0000x reference)
//
#include <hip/hip_runtime.h>

#define H 1024
#define S 65536

typedef float vfloat4 __attribute__((ext_vector_type(4)));

__device__ __forceinline__ vfloat4 nt_load4(const float* p) {
    return __builtin_nontemporal_load((const vfloat4*)p);
}
__device__ __forceinline__ float nt_load1(const float* p) {
    return __builtin_nontemporal_load(p);
}

// K1 (fused): v[j] = sum_i W[i][j] * h[i], ONE dispatch.
// 16 blocks; block b owns j in [b*64, b*64+64). Thread t: j = b*64+(t&63),
// g = t>>6 strides i by 4. Wave = 64 lanes reading 64 consecutive floats of
// one W row -> perfect 256 B coalescing. W read exactly once (NT, don't
// allocate); h (4 KB) is wave-uniform and cache-hot. Replaces the old
// k1a(128-block partial) + k1b(4-block serial reduce) pair: one fewer
// dispatch, no 512 KB partial round-trip, no latency-bound serial loop.
__global__ __launch_bounds__(256) void k1_gemv(const float* __restrict__ W,
                                               const float* __restrict__ hidden,
                                               float* __restrict__ v) {
    const int jl = threadIdx.x & 63;
    const int g  = threadIdx.x >> 6;
    const int j  = blockIdx.x * 64 + jl;
    float acc = 0.f;
    #pragma unroll 32
    for (int i = g; i < H; i += 4)
        acc += nt_load1(W + (size_t)i * H + j) * hidden[i];
    __shared__ float red[4][64];
    red[g][jl] = acc;
    __syncthreads();
    if (g == 0)
        v[j] = (red[0][jl] + red[1][jl]) + (red[2][jl] + red[3][jl]);
}

// K2: scores[row] = enc[row] . v, online (m,s) softmax state per wave.
// NT loads (measured: 360.7 vs 387.4 cached -- enc never cache-fits against
// the 1 GiB poison fills; allocating lines thrashes the LLC). Register
// double-buffer: two row-pairs (16 KB/wave) in flight across the reduce+exp
// chain. 1024 blocks x 4 waves x 16 rows. Measured ~6.7 TB/s effective.
__global__ __launch_bounds__(256) void k_scores(const float* __restrict__ enc,
                                                const float* __restrict__ v,
                                                float* __restrict__ scores,
                                                float* __restrict__ bmax,
                                                float* __restrict__ bsum) {
    const int lane = threadIdx.x & 63;
    const int warp = threadIdx.x >> 6;
    const vfloat4 vr0 = *(const vfloat4*)(v + lane * 4);
    const vfloat4 vr1 = *(const vfloat4*)(v + 256 + lane * 4);
    const vfloat4 vr2 = *(const vfloat4*)(v + 512 + lane * 4);
    const vfloat4 vr3 = *(const vfloat4*)(v + 768 + lane * 4);

    const int wg = blockIdx.x * 4 + warp;            // 0..4095
    const float* base = enc + (size_t)(wg * 2) * H + lane * 4;  // rows r0,r1 contiguous (8 KB)

    float m = -INFINITY;   // running max (per half-wave row stream)
    float s = 0.f;         // running sum of exp(score - m)

    vfloat4 A0, A1, A2, A3, A4, A5, A6, A7;
    vfloat4 B0, B1, B2, B3, B4, B5, B6, B7;

#define LOADB(P, IT) do { \
    const float* _p = base + (size_t)(IT) * 8192 * H; \
    P##0 = nt_load4(_p);        P##1 = nt_load4(_p + 256); \
    P##2 = nt_load4(_p + 512);  P##3 = nt_load4(_p + 768); \
    P##4 = nt_load4(_p + 1024); P##5 = nt_load4(_p + 1280); \
    P##6 = nt_load4(_p + 1536); P##7 = nt_load4(_p + 1792); \
} while (0)

#define COMP(P, IT) do { \
    const vfloat4 p0 = P##0 * vr0 + P##1 * vr1 + P##2 * vr2 + P##3 * vr3; \
    const vfloat4 p1 = P##4 * vr0 + P##5 * vr1 + P##6 * vr2 + P##7 * vr3; \
    float acc0 = (p0.x + p0.y) + (p0.z + p0.w); \
    float acc1 = (p1.x + p1.y) + (p1.z + p1.w); \
    const float t0 = __shfl_xor(acc0, 32, 64); \
    const float t1 = __shfl_xor(acc1, 32, 64); \
    float c = (lane < 32) ? (acc0 + t0) : (acc1 + t1); \
    c += __shfl_xor(c, 1, 64);  c += __shfl_xor(c, 2, 64); \
    c += __shfl_xor(c, 4, 64);  c += __shfl_xor(c, 8, 64); \
    c += __shfl_xor(c, 16, 64); \
    const int _r0 = wg * 2 + (IT) * 8192; \
    if (lane == 0)  scores[_r0] = c; \
    if (lane == 32) scores[_r0 + 1] = c; \
    const float _mn = fmaxf(m, c); \
    s = s * __expf(m - _mn) + __expf(c - _mn); \
    m = _mn; \
} while (0)

    // software pipeline: always 1-2 row-pairs of NT loads in flight
    LOADB(A, 0);
    LOADB(B, 1);
    COMP(A, 0);
    LOADB(A, 2);
    COMP(B, 1);
    LOADB(B, 3);
    COMP(A, 2);
    LOADB(A, 4);
    COMP(B, 3);
    LOADB(B, 5);
    COMP(A, 4);
    LOADB(A, 6);
    COMP(B, 5);
    LOADB(B, 7);
    COMP(A, 6);
    COMP(B, 7);

#undef LOADB
#undef COMP

    // merge the two half-wave (m, s) streams
    const float mo = __shfl_xor(m, 32, 64);
    const float so = __shfl_xor(s, 32, 64);
    const float mm2 = fmaxf(m, mo);
    s = s * __expf(m - mm2) + so * __expf(mo - mm2);
    m = mm2;

    __shared__ float smx[4], ssm[4];
    if (lane == 0) { smx[warp] = m; ssm[warp] = s; }
    __syncthreads();
    if (threadIdx.x == 0) {
        const float M = fmaxf(fmaxf(smx[0], smx[1]), fmaxf(smx[2], smx[3]));
        const float SS = ssm[0] * __expf(smx[0] - M) + ssm[1] * __expf(smx[1] - M)
                       + ssm[2] * __expf(smx[2] - M) + ssm[3] * __expf(smx[3] - M);
        bmax[blockIdx.x] = M;
        bsum[blockIdx.x] = SS;
    }
}

// K_final: every block redundantly reduces bmax/bsum[1024] -> (gmax, total)
// (8 KB, L2-hot), then the SINGLE pass: out[i] = exp(scores[i]-gmax)/total.
__global__ __launch_bounds__(256) void k_final(const float* __restrict__ scores,
                                               const float* __restrict__ bmax,
                                               const float* __restrict__ bsum,
                                               float* __restrict__ out) {
    const int t = threadIdx.x;
    const int lane = t & 63;
    const int warp = t >> 6;

    float lm[4];
    float m = -INFINITY;
    #pragma unroll
    for (int k = 0; k < 4; ++k) {
        lm[k] = bmax[t + k * 256];
        m = fmaxf(m, lm[k]);
    }
    #pragma unroll
    for (int d = 1; d < 64; d <<= 1) m = fmaxf(m, __shfl_xor(m, d, 64));
    __shared__ float sm[4];
    if (lane == 0) sm[warp] = m;
    __syncthreads();
    const float gmax = fmaxf(fmaxf(sm[0], sm[1]), fmaxf(sm[2], sm[3]));

    float p = 0.f;
    #pragma unroll
    for (int k = 0; k < 4; ++k) p += bsum[t + k * 256] * __expf(lm[k] - gmax);
    #pragma unroll
    for (int d = 1; d < 64; d <<= 1) p += __shfl_xor(p, d, 64);
    __shared__ float sp[4];
    if (lane == 0) sp[warp] = p;
    __syncthreads();
    const float inv = 1.0f / ((sp[0] + sp[1]) + (sp[2] + sp[3]));

    const int i = blockIdx.x * 256 + t;
    out[i] = __expf(scores[i] - gmax) * inv;
}

extern "C" void kernel_launch(void* const* d_in, const int* in_sizes, int n_in,
                              void* d_out, int out_size, void* d_ws, size_t ws_size,
                              hipStream_t stream) {
    const float* hidden = (const float*)d_in[0];
    const float* enc    = (const float*)d_in[1];
    const float* W      = (const float*)d_in[2];
    // d_in[3] = b: b.hidden is a uniform shift of all scores -> softmax-invariant, dropped.
    float* out = (float*)d_out;

    float* v       = (float*)d_ws;       // 1024
    float* scores  = v + 1024;           // 65536
    float* bmax    = scores + S;         // 1024
    float* bsum    = bmax + 1024;        // 1024

    k1_gemv <<<16,   256, 0, stream>>>(W, hidden, v);
    k_scores<<<1024, 256, 0, stream>>>(enc, v, scores, bmax, bsum);
    k_final <<<256,  256, 0, stream>>>(scores, bmax, bsum, out);
}